// Round 4
// baseline (792.735 us; speedup 1.0000x reference)
//
#include <hip/hip_runtime.h>
#include <math.h>

// ---------------- problem constants ----------------
constexpr int NN   = 20000;          // nodes
constexpr int NE   = 320000;         // edges
constexpr int ND   = 64;             // node dim
constexpr int ED   = 16;             // edge dim
constexpr int HID  = 256;
constexpr int HEADS= 8;
constexpr int CH   = 32;             // channels per head
constexpr int NB   = 16;             // graphs
constexpr int NL   = 3;              // layers
constexpr float NEG_SLOPE = 0.2f;

typedef unsigned short ushort_t;
typedef __attribute__((ext_vector_type(8))) short short8v;   // 8 bf16 (4 VGPRs)
typedef __attribute__((ext_vector_type(4))) float f32x4;     // MFMA acc

// ---------------- workspace layout (float units) ----------------
constexpr size_t OFF_H      = 0;                               // [NN][256] f32
constexpr size_t OFF_EA     = OFF_H      + (size_t)NN*HID;     // [NE][16] f32
constexpr size_t OFF_EACSR  = OFF_EA     + (size_t)NE*ED;      // [NE][16] f32 (CSR order)
constexpr size_t OFF_LOOPEA = OFF_EACSR  + (size_t)NE*ED;      // [NN][16] f32
constexpr size_t OFF_HG     = OFF_LOOPEA + (size_t)NN*ED;      // [NB][256] f32
constexpr size_t OFF_XLB    = OFF_HG     + (size_t)NB*HID;     // [NN][256] bf16 -> NN*128 floats
constexpr size_t OFF_XRB    = OFF_XLB    + (size_t)NN*HID/2;
constexpr size_t OFF_BT     = OFF_XRB    + (size_t)NN*HID/2;   // [6][256][256] bf16
constexpr size_t OFF_INT    = OFF_BT     + (size_t)6*HID*HID/2;
// int region (indexed in ints from OFF_INT)
constexpr size_t IOFF_DEG    = 0;
constexpr size_t IOFF_ROWOFF = IOFF_DEG    + NN;
constexpr size_t IOFF_CURSOR = IOFF_ROWOFF + NN + 1;
constexpr size_t IOFF_CSRSRC = IOFF_CURSOR + NN;
constexpr size_t IOFF_CSREID = IOFF_CSRSRC + NE;
constexpr size_t IOFF_CNT    = IOFF_CSREID + NE;

// ---------------- helpers ----------------
__device__ __forceinline__ ushort_t f2bf(float f) {            // RNE fp32->bf16
  unsigned u = __float_as_uint(f);
  u += 0x7FFFu + ((u >> 16) & 1u);
  return (ushort_t)(u >> 16);
}
__device__ __forceinline__ float bf2f(ushort_t u) {
  return __uint_as_float(((unsigned)u) << 16);
}
__device__ __forceinline__ float4 ld_bf4(const ushort_t* p) {
  ushort4 u = *(const ushort4*)p;
  return make_float4(bf2f(u.x), bf2f(u.y), bf2f(u.z), bf2f(u.w));
}

// ---------------- utility ----------------
__global__ __launch_bounds__(256) void k_zero(float* p, int n) {
  int i = blockIdx.x*256 + threadIdx.x;
  for (; i < n; i += gridDim.x*256) p[i] = 0.f;
}

// bf16-transposed weights: Bt[mat][n][k] = W[mat][k][n]; mat = l*2+z (z=0:Wl,1:Wr)
__global__ __launch_bounds__(256) void k_wt(const float* __restrict__ Wl,
    const float* __restrict__ Wr, ushort_t* __restrict__ Bt) {
  int i = blockIdx.x*256 + threadIdx.x;
  if (i >= 6*HID*HID) return;
  int mat = i >> 16, rem = i & 65535;
  int k = rem >> 8, n = rem & 255;          // consecutive threads -> consecutive n (coalesced read)
  int l = mat >> 1, z = mat & 1;
  const float* W = (z ? Wr : Wl) + (size_t)l*HID*HID;
  Bt[(size_t)mat*HID*HID + (size_t)n*HID + k] = f2bf(W[(size_t)k*HID + n]);
}

// h = x @ node_W + node_b   (x: [NN,64], W: [64,256])
__global__ __launch_bounds__(256) void k_node_embed(const float* __restrict__ x,
    const float* __restrict__ W, const float* __restrict__ b, float* __restrict__ h) {
  __shared__ float xs[4][ND];
  int n0 = blockIdx.x * 4;
  int tid = threadIdx.x;
  { int r = tid >> 6, j = tid & 63; xs[r][j] = x[(size_t)(n0+r)*ND + j]; }
  __syncthreads();
  int c = tid;
  float a0 = b[c], a1 = b[c], a2 = b[c], a3 = b[c];
  #pragma unroll 8
  for (int j = 0; j < ND; ++j) {
    float w = W[(size_t)j*HID + c];
    a0 += xs[0][j]*w; a1 += xs[1][j]*w; a2 += xs[2][j]*w; a3 += xs[3][j]*w;
  }
  h[(size_t)(n0+0)*HID+c]=a0; h[(size_t)(n0+1)*HID+c]=a1;
  h[(size_t)(n0+2)*HID+c]=a2; h[(size_t)(n0+3)*HID+c]=a3;
}

// ea = edge_attr @ edge_W + edge_b  (attr:[NE,16], W:[16,16])
__global__ __launch_bounds__(256) void k_edge_embed(const float* __restrict__ attr,
    const float* __restrict__ W, const float* __restrict__ b, float* __restrict__ ea) {
  int i = blockIdx.x*256 + threadIdx.x;
  const int total = NE * ED;
  for (; i < total; i += gridDim.x*256) {
    int e = i >> 4, c = i & 15;
    const float* row = attr + (size_t)e*ED;
    float acc = b[c];
    #pragma unroll
    for (int j = 0; j < ED; ++j) acc += row[j] * W[j*ED + c];
    ea[i] = acc;
  }
}

__global__ __launch_bounds__(256) void k_deg(const int* __restrict__ dst, int* deg) {
  int i = blockIdx.x*256 + threadIdx.x;
  for (; i < NE; i += gridDim.x*256) atomicAdd(&deg[dst[i]], 1);
}

// batch is sorted: cnt[b] = upper_bound(b) - lower_bound(b). No atomics.
__global__ __launch_bounds__(64) void k_cnt_bs(const int* __restrict__ batch, int* __restrict__ cnt) {
  int b = threadIdx.x;
  if (b >= NB) return;
  int lo = 0, hi = NN;
  while (lo < hi) { int mid = (lo+hi) >> 1; if (batch[mid] <  b) lo = mid+1; else hi = mid; }
  int lb = lo;
  lo = 0; hi = NN;
  while (lo < hi) { int mid = (lo+hi) >> 1; if (batch[mid] <= b) lo = mid+1; else hi = mid; }
  cnt[b] = lo - lb;
}

// single-block scan of deg -> row_off (excl prefix) + cursor copy; row_off[NN]=E
__global__ __launch_bounds__(1024) void k_scan(const int* __restrict__ deg,
    int* __restrict__ row_off, int* __restrict__ cursor) {
  __shared__ int sm[1024];
  const int CHK = (NN + 1023) / 1024;   // 20
  int t = threadIdx.x;
  int base = t * CHK;
  int s = 0;
  for (int i = 0; i < CHK; ++i) { int idx = base+i; if (idx < NN) s += deg[idx]; }
  sm[t] = s; __syncthreads();
  for (int off = 1; off < 1024; off <<= 1) {
    int v = (t >= off) ? sm[t-off] : 0;
    __syncthreads();
    sm[t] += v;
    __syncthreads();
  }
  int run = (t == 0) ? 0 : sm[t-1];
  for (int i = 0; i < CHK; ++i) {
    int idx = base+i;
    if (idx < NN) { row_off[idx] = run; cursor[idx] = run; run += deg[idx]; }
  }
  if (t == 1023) row_off[NN] = sm[1023];
}

__global__ __launch_bounds__(256) void k_fill(const int* __restrict__ src, const int* __restrict__ dst,
    int* cursor, int* __restrict__ csr_src, int* __restrict__ csr_eid) {
  int e = blockIdx.x*256 + threadIdx.x;
  for (; e < NE; e += gridDim.x*256) {
    int pos = atomicAdd(&cursor[dst[e]], 1);
    csr_src[pos] = src[e];
    csr_eid[pos] = e;
  }
}

// gather ea into CSR order (layer-invariant): ea_csr[k][c] = ea[csr_eid[k]][c]
__global__ __launch_bounds__(256) void k_eacsr(const float* __restrict__ ea,
    const int* __restrict__ csr_eid, float* __restrict__ ea_csr) {
  int i = blockIdx.x*256 + threadIdx.x;
  const int total = NE * ED;
  for (; i < total; i += gridDim.x*256) {
    int k = i >> 4, c = i & 15;
    ea_csr[i] = ea[(size_t)csr_eid[k]*ED + c];
  }
}

// loop_ea[n,c] = mean of ea_csr rows in [row_off[n], row_off[n+1])  (sequential reads)
__global__ __launch_bounds__(256) void k_loopea(const float* __restrict__ ea_csr,
    const int* __restrict__ row_off, float* __restrict__ loopea) {
  int i = blockIdx.x*256 + threadIdx.x;
  const int total = NN * ED;
  for (; i < total; i += gridDim.x*256) {
    int n = i >> 4, c = i & 15;
    int b0 = row_off[n], b1 = row_off[n+1];
    float s = 0.f;
    for (int k = b0; k < b1; ++k) s += ea_csr[(size_t)k*ED + c];
    int dg = b1 - b0;
    loopea[i] = s / (float)(dg > 1 ? dg : 1);
  }
}

// ---------------- bf16 MFMA dual GEMM ----------------
// C{z} = bf16( h @ W{z} + bias{z} );  h:[M,256] f32, Bt: pre-transposed bf16 [2][n=256][k=256]
// grid (ceil(M/128), 2); 256 thr = 4 waves (2x2), wave tile 64x128, frags via direct global loads.
__global__ __launch_bounds__(256) void k_gemm_mfma(const float* __restrict__ A,
    const ushort_t* __restrict__ Bt,
    const float* __restrict__ bias0, const float* __restrict__ bias1,
    ushort_t* __restrict__ C0, ushort_t* __restrict__ C1, int M) {
  int z = blockIdx.y;
  const ushort_t* B = Bt + (size_t)z*HID*HID;
  const float* bias = z ? bias1 : bias0;
  ushort_t* C       = z ? C1 : C0;
  int tid = threadIdx.x;
  int w = tid >> 6, lane = tid & 63;
  int wr = w >> 1, wc = w & 1;
  int l15 = lane & 15, kg = lane >> 4;
  int m0 = blockIdx.x * 128;

  f32x4 acc[4][8];
  #pragma unroll
  for (int mi = 0; mi < 4; ++mi)
    #pragma unroll
    for (int ni = 0; ni < 8; ++ni)
      acc[mi][ni] = (f32x4){0.f,0.f,0.f,0.f};

  for (int k0 = 0; k0 < HID; k0 += 32) {
    short8v a[4];
    #pragma unroll
    for (int mi = 0; mi < 4; ++mi) {
      int row = m0 + wr*64 + mi*16 + l15;          // OOB rows read garbage inside ws; stores guarded
      const float* ap = A + (size_t)row*HID + k0 + kg*8;
      float4 f0 = *(const float4*)ap;
      float4 f1 = *(const float4*)(ap+4);
      short8v av;
      av[0]=(short)f2bf(f0.x); av[1]=(short)f2bf(f0.y); av[2]=(short)f2bf(f0.z); av[3]=(short)f2bf(f0.w);
      av[4]=(short)f2bf(f1.x); av[5]=(short)f2bf(f1.y); av[6]=(short)f2bf(f1.z); av[7]=(short)f2bf(f1.w);
      a[mi] = av;
    }
    #pragma unroll
    for (int ni = 0; ni < 8; ++ni) {
      int col = wc*128 + ni*16 + l15;
      short8v b = *(const short8v*)(B + (size_t)col*HID + k0 + kg*8);
      #pragma unroll
      for (int mi = 0; mi < 4; ++mi)
        acc[mi][ni] = __builtin_amdgcn_mfma_f32_16x16x32_bf16(a[mi], b, acc[mi][ni], 0, 0, 0);
    }
  }
  // epilogue: D col = lane&15, row = (lane>>4)*4 + r  [verified m89 layout]
  #pragma unroll
  for (int ni = 0; ni < 8; ++ni) {
    int col = wc*128 + ni*16 + l15;
    float bs = bias[col];
    #pragma unroll
    for (int mi = 0; mi < 4; ++mi) {
      #pragma unroll
      for (int r = 0; r < 4; ++r) {
        int row = m0 + wr*64 + mi*16 + kg*4 + r;
        if (row < M) C[(size_t)row*HID + col] = f2bf(acc[mi][ni][r] + bs);
      }
    }
  }
}

// ---- fused GATv2 attention: online softmax + aggregation, one wave per dst node ----
__device__ __forceinline__ float4 eemb16(const float4* __restrict__ w,
    float4 a, float4 b, float4 c, float4 d) {
  float e[16] = {a.x,a.y,a.z,a.w, b.x,b.y,b.z,b.w, c.x,c.y,c.z,c.w, d.x,d.y,d.z,d.w};
  float4 r = make_float4(0.f,0.f,0.f,0.f);
  #pragma unroll
  for (int j = 0; j < 16; ++j) {
    r.x += e[j]*w[j].x; r.y += e[j]*w[j].y; r.z += e[j]*w[j].z; r.w += e[j]*w[j].w;
  }
  return r;
}

__device__ __forceinline__ float head_logit(float4 z, float4 av) {
  float z0 = z.x > 0.f ? z.x : z.x*NEG_SLOPE;
  float z1 = z.y > 0.f ? z.y : z.y*NEG_SLOPE;
  float z2 = z.z > 0.f ? z.z : z.z*NEG_SLOPE;
  float z3 = z.w > 0.f ? z.w : z.w*NEG_SLOPE;
  float p = z0*av.x + z1*av.y + z2*av.z + z3*av.w;
  p += __shfl_xor(p, 1);
  p += __shfl_xor(p, 2);
  p += __shfl_xor(p, 4);
  return p;
}

__global__ __launch_bounds__(256) void k_gat_fused(
    const ushort_t* __restrict__ xlb, const ushort_t* __restrict__ xrb,
    const float* __restrict__ ea_csr, const float* __restrict__ loopea,
    const int* __restrict__ row_off, const int* __restrict__ csr_src,
    const float* __restrict__ We, const float* __restrict__ att,
    const float* __restrict__ bias, float* __restrict__ h) {
  int lane = threadIdx.x & 63;
  int n = (blockIdx.x*256 + threadIdx.x) >> 6;
  if (n >= NN) return;
  int c4 = lane*4;
  int hh = lane >> 3;
  float4 wv[16];
  #pragma unroll
  for (int j = 0; j < 16; ++j) wv[j] = *(const float4*)(We + (size_t)j*HID + c4);
  float4 av  = *(const float4*)(att + hh*CH + (lane&7)*4);
  float4 xr4 = ld_bf4(xrb + (size_t)n*HID + c4);
  float4 xls = ld_bf4(xlb + (size_t)n*HID + c4);

  // self-loop initializes the online softmax state
  float m, denom; float4 acc;
  {
    const float* lp = loopea + (size_t)n*ED;
    float4 l0 = *(const float4*)(lp+0), l1 = *(const float4*)(lp+4);
    float4 l2 = *(const float4*)(lp+8), l3 = *(const float4*)(lp+12);
    float4 em = eemb16(wv, l0, l1, l2, l3);
    float4 z = make_float4(xls.x+xr4.x+em.x, xls.y+xr4.y+em.y,
                           xls.z+xr4.z+em.z, xls.w+xr4.w+em.w);
    m = head_logit(z, av);
    denom = 1.f;
    acc = xls;
  }

  int b0 = row_off[n], b1 = row_off[n+1];
  for (int kb = b0; kb < b1; kb += 64) {
    int nk = min(64, b1 - kb);
    int si = 0;
    if (lane < nk) si = csr_src[kb+lane];
    // software pipeline: issue edge-0 loads
    int s0 = __shfl(si, 0);
    ushort4 xnu = *(const ushort4*)(xlb + (size_t)s0*HID + c4);
    const float* ep = ea_csr + (size_t)kb*ED;
    float4 a0 = *(const float4*)(ep+0), a1 = *(const float4*)(ep+4);
    float4 a2 = *(const float4*)(ep+8), a3 = *(const float4*)(ep+12);
    for (int t = 0; t < nk; ++t) {
      ushort4 xcu = xnu;
      float4 c0 = a0, c1 = a1, c2 = a2, c3 = a3;
      if (t+1 < nk) {
        int s2 = __shfl(si, t+1);
        xnu = *(const ushort4*)(xlb + (size_t)s2*HID + c4);
        const float* ep2 = ea_csr + (size_t)(kb+t+1)*ED;
        a0 = *(const float4*)(ep2+0); a1 = *(const float4*)(ep2+4);
        a2 = *(const float4*)(ep2+8); a3 = *(const float4*)(ep2+12);
      }
      float4 xc = make_float4(bf2f(xcu.x), bf2f(xcu.y), bf2f(xcu.z), bf2f(xcu.w));
      float4 em = eemb16(wv, c0, c1, c2, c3);
      float4 z = make_float4(xc.x+xr4.x+em.x, xc.y+xr4.y+em.y,
                             xc.z+xr4.z+em.z, xc.w+xr4.w+em.w);
      float p = head_logit(z, av);
      float nm = fmaxf(m, p);
      float so = __expf(m - nm);
      float sn = __expf(p - nm);
      denom = denom*so + sn;
      acc.x = acc.x*so + sn*xc.x;
      acc.y = acc.y*so + sn*xc.y;
      acc.z = acc.z*so + sn*xc.z;
      acc.w = acc.w*so + sn*xc.w;
      m = nm;
    }
  }
  float inv = 1.f / denom;
  float* hp = h + (size_t)n*HID + c4;
  float4 hv = *(const float4*)hp;
  float4 b4 = *(const float4*)(bias + c4);
  hv.x += acc.x*inv + b4.x;
  hv.y += acc.y*inv + b4.y;
  hv.z += acc.z*inv + b4.z;
  hv.w += acc.w*inv + b4.w;
  *(float4*)hp = hv;
}

// mean-pool numerator: run-accumulated atomics (batch is sorted)
__global__ __launch_bounds__(256) void k_pool(const float* __restrict__ h,
    const int* __restrict__ batch, float* __restrict__ hg) {
  int c = threadIdx.x;
  int per = (NN + gridDim.x - 1) / gridDim.x;
  int n0 = blockIdx.x * per, n1 = min(NN, n0 + per);
  if (n0 >= n1) return;
  int cur = batch[n0];
  float acc = 0.f;
  for (int n = n0; n < n1; ++n) {
    int b = batch[n];
    if (b != cur) { atomicAdd(&hg[(size_t)cur*HID + c], acc); acc = 0.f; cur = b; }
    acc += h[(size_t)n*HID + c];
  }
  atomicAdd(&hg[(size_t)cur*HID + c], acc);
}

// out = gelu(hg/cnt @ W1 + b1) @ W2 + b2 ; one block per graph
__global__ __launch_bounds__(256) void k_mlp(const float* __restrict__ hg, const int* __restrict__ cnt,
    const float* __restrict__ W1, const float* __restrict__ b1,
    const float* __restrict__ W2, const float* __restrict__ b2, float* __restrict__ out) {
  __shared__ float row[HID];
  __shared__ float zrow[HID];
  int b = blockIdx.x, c = threadIdx.x;
  float cn = (float)cnt[b]; cn = cn < 1.f ? 1.f : cn;
  row[c] = hg[(size_t)b*HID + c] / cn;
  __syncthreads();
  float acc = b1[c];
  for (int j = 0; j < HID; ++j) acc += row[j] * W1[(size_t)j*HID + c];
  float g = 0.5f * acc * (1.f + erff(acc * 0.70710678118654752440f));
  zrow[c] = g;
  __syncthreads();
  float acc2 = b2[c];
  for (int j = 0; j < HID; ++j) acc2 += zrow[j] * W2[(size_t)j*HID + c];
  out[(size_t)b*HID + c] = acc2;
}

extern "C" void kernel_launch(void* const* d_in, const int* in_sizes, int n_in,
                              void* d_out, int out_size, void* d_ws, size_t ws_size,
                              hipStream_t stream) {
  const float* x         = (const float*)d_in[0];
  const int*   edge_index= (const int*)  d_in[1];
  const float* edge_attr = (const float*)d_in[2];
  const int*   batch     = (const int*)  d_in[3];
  const float* node_W    = (const float*)d_in[4];
  const float* node_b    = (const float*)d_in[5];
  const float* edge_W    = (const float*)d_in[6];
  const float* edge_b    = (const float*)d_in[7];
  const float* Wl        = (const float*)d_in[8];
  const float* bl        = (const float*)d_in[9];
  const float* Wr        = (const float*)d_in[10];
  const float* br        = (const float*)d_in[11];
  const float* We        = (const float*)d_in[12];
  const float* att       = (const float*)d_in[13];
  const float* conv_bias = (const float*)d_in[14];
  const float* W1        = (const float*)d_in[15];
  const float* b1        = (const float*)d_in[16];
  const float* W2        = (const float*)d_in[17];
  const float* b2        = (const float*)d_in[18];
  const int* srcp = edge_index;
  const int* dstp = edge_index + NE;

  float* ws = (float*)d_ws;
  float* h      = ws + OFF_H;
  float* ea     = ws + OFF_EA;
  float* ea_csr = ws + OFF_EACSR;
  float* loopea = ws + OFF_LOOPEA;
  float* hg     = ws + OFF_HG;
  ushort_t* xlb = (ushort_t*)(ws + OFF_XLB);
  ushort_t* xrb = (ushort_t*)(ws + OFF_XRB);
  ushort_t* Bt  = (ushort_t*)(ws + OFF_BT);
  int* ib       = (int*)(ws + OFF_INT);
  int* deg      = ib + IOFF_DEG;
  int* row_off  = ib + IOFF_ROWOFF;
  int* cursor   = ib + IOFF_CURSOR;
  int* csr_src  = ib + IOFF_CSRSRC;
  int* csr_eid  = ib + IOFF_CSREID;
  int* cnt      = ib + IOFF_CNT;

  // zero accumulators (must happen every launch; harness doesn't re-poison)
  k_zero<<<8, 256, 0, stream>>>(hg, NB*HID);
  k_zero<<<80, 256, 0, stream>>>((float*)deg, NN);

  k_wt<<<(6*HID*HID + 255)/256, 256, 0, stream>>>(Wl, Wr, Bt);
  k_node_embed<<<NN/4, 256, 0, stream>>>(x, node_W, node_b, h);
  k_edge_embed<<<2048, 256, 0, stream>>>(edge_attr, edge_W, edge_b, ea);
  k_deg<<<1250, 256, 0, stream>>>(dstp, deg);
  k_cnt_bs<<<1, 64, 0, stream>>>(batch, cnt);
  k_scan<<<1, 1024, 0, stream>>>(deg, row_off, cursor);
  k_fill<<<1250, 256, 0, stream>>>(srcp, dstp, cursor, csr_src, csr_eid);
  k_eacsr<<<2048, 256, 0, stream>>>(ea, csr_eid, ea_csr);
  k_loopea<<<1250, 256, 0, stream>>>(ea_csr, row_off, loopea);

  for (int l = 0; l < NL; ++l) {
    dim3 g((NN + 127)/128, 2);
    k_gemm_mfma<<<g, 256, 0, stream>>>(h, Bt + (size_t)l*2*HID*HID,
        bl + (size_t)l*HID, br + (size_t)l*HID, xlb, xrb, NN);
    k_gat_fused<<<(NN*64 + 255)/256, 256, 0, stream>>>(xlb, xrb, ea_csr, loopea,
        row_off, csr_src,
        We + (size_t)l*ED*HID, att + (size_t)l*HEADS*CH,
        conv_bias + (size_t)l*HID, h);
  }

  k_pool<<<80, 256, 0, stream>>>(h, batch, hg);
  k_mlp<<<NB, 256, 0, stream>>>(hg, cnt, W1, b1, W2, b2, (float*)d_out);
}

// Round 5
// 645.859 us; speedup vs baseline: 1.2274x; 1.2274x over previous
//
#include <hip/hip_runtime.h>
#include <math.h>

// ---------------- problem constants ----------------
constexpr int NN   = 20000;          // nodes
constexpr int NE   = 320000;         // edges
constexpr int ND   = 64;             // node dim
constexpr int ED   = 16;             // edge dim
constexpr int HID  = 256;
constexpr int HEADS= 8;
constexpr int CH   = 32;             // channels per head
constexpr int NB   = 16;             // graphs
constexpr int NL   = 3;              // layers
constexpr float NEG_SLOPE = 0.2f;

typedef unsigned short ushort_t;
typedef __attribute__((ext_vector_type(8))) short short8v;   // 8 bf16 (4 VGPRs)
typedef __attribute__((ext_vector_type(4))) float f32x4;     // MFMA acc

// ---------------- workspace layout (float units) ----------------
constexpr size_t OFF_H      = 0;                               // [NN][256] f32
constexpr size_t OFF_HB     = OFF_H      + (size_t)NN*HID;     // [NN][256] bf16
constexpr size_t OFF_EACSR  = OFF_HB     + (size_t)NN*HID/2;   // [NE][16] f32 (CSR order)
constexpr size_t OFF_LOOPEA = OFF_EACSR  + (size_t)NE*ED;      // [NN][16] f32
constexpr size_t OFF_HG     = OFF_LOOPEA + (size_t)NN*ED;      // [NB][256] f32
constexpr size_t OFF_XLB    = OFF_HG     + (size_t)NB*HID;     // [NN][256] bf16
constexpr size_t OFF_XRB    = OFF_XLB    + (size_t)NN*HID/2;
constexpr size_t OFF_BT     = OFF_XRB    + (size_t)NN*HID/2;   // [6][256][256] bf16
constexpr size_t OFF_INT    = OFF_BT     + (size_t)6*HID*HID/2;
// int region (indexed in ints from OFF_INT)
constexpr size_t IOFF_DEG    = 0;
constexpr size_t IOFF_ROWOFF = IOFF_DEG    + NN;
constexpr size_t IOFF_CURSOR = IOFF_ROWOFF + NN + 1;
constexpr size_t IOFF_CSRSRC = IOFF_CURSOR + NN;
constexpr size_t IOFF_CSREID = IOFF_CSRSRC + NE;
constexpr size_t IOFF_CNT    = IOFF_CSREID + NE;

// ---------------- helpers ----------------
__device__ __forceinline__ ushort_t f2bf(float f) {            // RNE fp32->bf16
  unsigned u = __float_as_uint(f);
  u += 0x7FFFu + ((u >> 16) & 1u);
  return (ushort_t)(u >> 16);
}
__device__ __forceinline__ float bf2f(ushort_t u) {
  return __uint_as_float(((unsigned)u) << 16);
}
__device__ __forceinline__ float4 ld_bf4(const ushort_t* p) {
  ushort4 u = *(const ushort4*)p;
  return make_float4(bf2f(u.x), bf2f(u.y), bf2f(u.z), bf2f(u.w));
}

// ---------------- utility ----------------
__global__ __launch_bounds__(256) void k_zero(float* p, int n) {
  int i = blockIdx.x*256 + threadIdx.x;
  for (; i < n; i += gridDim.x*256) p[i] = 0.f;
}

// bf16-transposed weights: Bt[mat][n][k] = W[mat][k][n]; mat = l*2+z (z=0:Wl,1:Wr)
__global__ __launch_bounds__(256) void k_wt(const float* __restrict__ Wl,
    const float* __restrict__ Wr, ushort_t* __restrict__ Bt) {
  int i = blockIdx.x*256 + threadIdx.x;
  if (i >= 6*HID*HID) return;
  int mat = i >> 16, rem = i & 65535;
  int k = rem >> 8, n = rem & 255;
  int l = mat >> 1, z = mat & 1;
  const float* W = (z ? Wr : Wl) + (size_t)l*HID*HID;
  Bt[(size_t)mat*HID*HID + (size_t)n*HID + k] = f2bf(W[(size_t)k*HID + n]);
}

// h = x @ node_W + node_b; also writes bf16 mirror hb
__global__ __launch_bounds__(256) void k_node_embed(const float* __restrict__ x,
    const float* __restrict__ W, const float* __restrict__ b,
    float* __restrict__ h, ushort_t* __restrict__ hb) {
  __shared__ float xs[4][ND];
  int n0 = blockIdx.x * 4;
  int tid = threadIdx.x;
  { int r = tid >> 6, j = tid & 63; xs[r][j] = x[(size_t)(n0+r)*ND + j]; }
  __syncthreads();
  int c = tid;
  float a0 = b[c], a1 = b[c], a2 = b[c], a3 = b[c];
  #pragma unroll 8
  for (int j = 0; j < ND; ++j) {
    float w = W[(size_t)j*HID + c];
    a0 += xs[0][j]*w; a1 += xs[1][j]*w; a2 += xs[2][j]*w; a3 += xs[3][j]*w;
  }
  h[(size_t)(n0+0)*HID+c]=a0; h[(size_t)(n0+1)*HID+c]=a1;
  h[(size_t)(n0+2)*HID+c]=a2; h[(size_t)(n0+3)*HID+c]=a3;
  hb[(size_t)(n0+0)*HID+c]=f2bf(a0); hb[(size_t)(n0+1)*HID+c]=f2bf(a1);
  hb[(size_t)(n0+2)*HID+c]=f2bf(a2); hb[(size_t)(n0+3)*HID+c]=f2bf(a3);
}

__global__ __launch_bounds__(256) void k_deg(const int* __restrict__ dst, int* deg) {
  int i = blockIdx.x*256 + threadIdx.x;
  for (; i < NE; i += gridDim.x*256) atomicAdd(&deg[dst[i]], 1);
}

// batch is sorted: cnt[b] = upper_bound(b) - lower_bound(b). No atomics.
__global__ __launch_bounds__(64) void k_cnt_bs(const int* __restrict__ batch, int* __restrict__ cnt) {
  int b = threadIdx.x;
  if (b >= NB) return;
  int lo = 0, hi = NN;
  while (lo < hi) { int mid = (lo+hi) >> 1; if (batch[mid] <  b) lo = mid+1; else hi = mid; }
  int lb = lo;
  lo = 0; hi = NN;
  while (lo < hi) { int mid = (lo+hi) >> 1; if (batch[mid] <= b) lo = mid+1; else hi = mid; }
  cnt[b] = lo - lb;
}

// single-block scan of deg -> row_off (excl prefix) + cursor copy; row_off[NN]=E
__global__ __launch_bounds__(1024) void k_scan(const int* __restrict__ deg,
    int* __restrict__ row_off, int* __restrict__ cursor) {
  __shared__ int sm[1024];
  const int CHK = (NN + 1023) / 1024;   // 20
  int t = threadIdx.x;
  int base = t * CHK;
  int s = 0;
  for (int i = 0; i < CHK; ++i) { int idx = base+i; if (idx < NN) s += deg[idx]; }
  sm[t] = s; __syncthreads();
  for (int off = 1; off < 1024; off <<= 1) {
    int v = (t >= off) ? sm[t-off] : 0;
    __syncthreads();
    sm[t] += v;
    __syncthreads();
  }
  int run = (t == 0) ? 0 : sm[t-1];
  for (int i = 0; i < CHK; ++i) {
    int idx = base+i;
    if (idx < NN) { row_off[idx] = run; cursor[idx] = run; run += deg[idx]; }
  }
  if (t == 1023) row_off[NN] = sm[1023];
}

__global__ __launch_bounds__(256) void k_fill(const int* __restrict__ src, const int* __restrict__ dst,
    int* cursor, int* __restrict__ csr_src, int* __restrict__ csr_eid) {
  int e = blockIdx.x*256 + threadIdx.x;
  for (; e < NE; e += gridDim.x*256) {
    int pos = atomicAdd(&cursor[dst[e]], 1);
    csr_src[pos] = src[e];
    csr_eid[pos] = e;
  }
}

// fused: ea rows (edge_attr @ edge_W + edge_b) in CSR order + per-node mean (loopea).
// one wave per node; 4 edges per iteration (16 lanes each).
__global__ __launch_bounds__(256) void k_edge_prep(const float* __restrict__ edge_attr,
    const float* __restrict__ edge_W, const float* __restrict__ edge_b,
    const int* __restrict__ row_off, const int* __restrict__ csr_eid,
    float* __restrict__ ea_csr, float* __restrict__ loopea) {
  int lane = threadIdx.x & 63;
  int n = (blockIdx.x*256 + threadIdx.x) >> 6;
  if (n >= NN) return;
  int e4 = lane >> 4, c = lane & 15;
  float Wc[16];
  #pragma unroll
  for (int j = 0; j < 16; ++j) Wc[j] = edge_W[j*ED + c];
  float bc = edge_b[c];
  int b0 = row_off[n], b1 = row_off[n+1];
  float sum = 0.f;
  for (int kb = b0; kb < b1; kb += 4) {
    int k = kb + e4;
    bool ok = (k < b1);
    int eid = ok ? csr_eid[k] : 0;
    float avv = ok ? edge_attr[(size_t)eid*ED + c] : 0.f;
    float r = bc;
    #pragma unroll
    for (int j = 0; j < 16; ++j) {
      float aj = __shfl(avv, (e4 << 4) + j);
      r += aj * Wc[j];
    }
    if (ok) { ea_csr[(size_t)k*ED + c] = r; sum += r; }
  }
  sum += __shfl_xor(sum, 16);
  sum += __shfl_xor(sum, 32);
  if (lane < 16) {
    int dg = b1 - b0;
    loopea[(size_t)n*ED + c] = sum / (float)(dg > 1 ? dg : 1);
  }
}

// ---------------- bf16 MFMA dual GEMM, LDS-staged A ----------------
// C{z} = bf16( hb @ W{z} + bias{z} ); block = 64 rows x full N=256, 4 waves (64 cols each)
__global__ __launch_bounds__(256) void k_gemm_bf16(const ushort_t* __restrict__ hb,
    const ushort_t* __restrict__ Bt,
    const float* __restrict__ bias0, const float* __restrict__ bias1,
    ushort_t* __restrict__ C0, ushort_t* __restrict__ C1, int M) {
  __shared__ ushort_t As[64][40];            // +8 bf16 pad -> 80B rows, 2-way banks (free)
  int z = blockIdx.y;
  const ushort_t* B = Bt + (size_t)z*HID*HID;
  const float* bias = z ? bias1 : bias0;
  ushort_t* C       = z ? C1 : C0;
  int tid = threadIdx.x;
  int w = tid >> 6, lane = tid & 63, l15 = lane & 15, kg = lane >> 4;
  int m0 = blockIdx.x * 64;

  f32x4 acc[4][4];
  #pragma unroll
  for (int mi = 0; mi < 4; ++mi)
    #pragma unroll
    for (int ni = 0; ni < 4; ++ni)
      acc[mi][ni] = (f32x4){0.f,0.f,0.f,0.f};

  int srow = tid >> 2, sko = (tid & 3) * 8;
  int grow = m0 + srow; if (grow >= M) grow = M - 1;
  const float4* gsrc = (const float4*)(hb + (size_t)grow*HID + sko);  // 8 bf16 per float4

  for (int k0 = 0; k0 < HID; k0 += 32) {
    *(float4*)&As[srow][sko] = gsrc[k0 >> 3];
    __syncthreads();
    short8v a[4], b[4];
    #pragma unroll
    for (int mi = 0; mi < 4; ++mi)
      a[mi] = *(const short8v*)&As[mi*16 + l15][kg*8];
    #pragma unroll
    for (int ni = 0; ni < 4; ++ni)
      b[ni] = *(const short8v*)(B + (size_t)(w*64 + ni*16 + l15)*HID + k0 + kg*8);
    #pragma unroll
    for (int mi = 0; mi < 4; ++mi)
      #pragma unroll
      for (int ni = 0; ni < 4; ++ni)
        acc[mi][ni] = __builtin_amdgcn_mfma_f32_16x16x32_bf16(a[mi], b[ni], acc[mi][ni], 0, 0, 0);
    __syncthreads();
  }
  // epilogue: D col = lane&15 (n-dim), row = (lane>>4)*4 + r (m-dim)  [verified R4]
  #pragma unroll
  for (int ni = 0; ni < 4; ++ni) {
    int col = w*64 + ni*16 + l15;
    float bs = bias[col];
    #pragma unroll
    for (int mi = 0; mi < 4; ++mi) {
      #pragma unroll
      for (int r = 0; r < 4; ++r) {
        int row = m0 + mi*16 + kg*4 + r;
        if (row < M) C[(size_t)row*HID + col] = f2bf(acc[mi][ni][r] + bs);
      }
    }
  }
}

// ---- fused GATv2 attention: online softmax, 2-edge unrolled; one wave per dst node ----
__device__ __forceinline__ float4 eemb16(const float4* __restrict__ w,
    float4 a, float4 b, float4 c, float4 d) {
  float e[16] = {a.x,a.y,a.z,a.w, b.x,b.y,b.z,b.w, c.x,c.y,c.z,c.w, d.x,d.y,d.z,d.w};
  float4 r = make_float4(0.f,0.f,0.f,0.f);
  #pragma unroll
  for (int j = 0; j < 16; ++j) {
    r.x += e[j]*w[j].x; r.y += e[j]*w[j].y; r.z += e[j]*w[j].z; r.w += e[j]*w[j].w;
  }
  return r;
}

__device__ __forceinline__ float head_logit(float4 z, float4 av) {
  float z0 = z.x > 0.f ? z.x : z.x*NEG_SLOPE;
  float z1 = z.y > 0.f ? z.y : z.y*NEG_SLOPE;
  float z2 = z.z > 0.f ? z.z : z.z*NEG_SLOPE;
  float z3 = z.w > 0.f ? z.w : z.w*NEG_SLOPE;
  float p = z0*av.x + z1*av.y + z2*av.z + z3*av.w;
  p += __shfl_xor(p, 1);
  p += __shfl_xor(p, 2);
  p += __shfl_xor(p, 4);
  return p;
}

__global__ __launch_bounds__(256) void k_gat_fused(
    const ushort_t* __restrict__ xlb, const ushort_t* __restrict__ xrb,
    const float* __restrict__ ea_csr, const float* __restrict__ loopea,
    const int* __restrict__ row_off, const int* __restrict__ csr_src,
    const float* __restrict__ We, const float* __restrict__ att,
    const float* __restrict__ bias, float* __restrict__ h, ushort_t* __restrict__ hb) {
  int lane = threadIdx.x & 63;
  int n = (blockIdx.x*256 + threadIdx.x) >> 6;
  if (n >= NN) return;
  int c4 = lane*4;
  int hh = lane >> 3;
  float4 wv[16];
  #pragma unroll
  for (int j = 0; j < 16; ++j) wv[j] = *(const float4*)(We + (size_t)j*HID + c4);
  float4 av  = *(const float4*)(att + hh*CH + (lane&7)*4);
  float4 xr4 = ld_bf4(xrb + (size_t)n*HID + c4);
  float4 xls = ld_bf4(xlb + (size_t)n*HID + c4);

  // self-loop initializes the online softmax state
  float m, denom; float4 acc;
  {
    const float* lp = loopea + (size_t)n*ED;
    float4 l0 = *(const float4*)(lp+0), l1 = *(const float4*)(lp+4);
    float4 l2 = *(const float4*)(lp+8), l3 = *(const float4*)(lp+12);
    float4 em = eemb16(wv, l0, l1, l2, l3);
    float4 z = make_float4(xls.x+xr4.x+em.x, xls.y+xr4.y+em.y,
                           xls.z+xr4.z+em.z, xls.w+xr4.w+em.w);
    m = head_logit(z, av);
    denom = 1.f;
    acc = xls;
  }

  int b0 = row_off[n], b1 = row_off[n+1];
  for (int kb = b0; kb < b1; kb += 64) {
    int nk = min(64, b1 - kb);
    int si = (lane < nk) ? csr_src[kb+lane] : 0;
    const float* ep = ea_csr + (size_t)kb*ED;
    ushort4 x0u = make_ushort4(0,0,0,0), x1u = make_ushort4(0,0,0,0);
    { int s = __shfl(si, 0); x0u = *(const ushort4*)(xlb + (size_t)s*HID + c4); }
    if (nk > 1) { int s = __shfl(si, 1); x1u = *(const ushort4*)(xlb + (size_t)s*HID + c4); }
    int t = 0;
    for (; t + 2 <= nk; t += 2) {
      ushort4 xau = x0u, xbu = x1u;
      if (t + 2 < nk) {
        int s = __shfl(si, t+2); x0u = *(const ushort4*)(xlb + (size_t)s*HID + c4);
        if (t + 3 < nk) { int s2 = __shfl(si, t+3); x1u = *(const ushort4*)(xlb + (size_t)s2*HID + c4); }
      }
      const float* e0 = ep + (size_t)t*ED;
      float4 c0 = *(const float4*)(e0+0),  c1 = *(const float4*)(e0+4);
      float4 c2 = *(const float4*)(e0+8),  c3 = *(const float4*)(e0+12);
      float4 d0 = *(const float4*)(e0+16), d1 = *(const float4*)(e0+20);
      float4 d2 = *(const float4*)(e0+24), d3 = *(const float4*)(e0+28);
      float4 xa = make_float4(bf2f(xau.x), bf2f(xau.y), bf2f(xau.z), bf2f(xau.w));
      float4 xb = make_float4(bf2f(xbu.x), bf2f(xbu.y), bf2f(xbu.z), bf2f(xbu.w));
      float4 em0 = eemb16(wv, c0, c1, c2, c3);
      float4 em1 = eemb16(wv, d0, d1, d2, d3);
      float4 z0 = make_float4(xa.x+xr4.x+em0.x, xa.y+xr4.y+em0.y, xa.z+xr4.z+em0.z, xa.w+xr4.w+em0.w);
      float4 z1 = make_float4(xb.x+xr4.x+em1.x, xb.y+xr4.y+em1.y, xb.z+xr4.z+em1.z, xb.w+xr4.w+em1.w);
      float p0 = head_logit(z0, av);
      float p1 = head_logit(z1, av);
      float nm = fmaxf(fmaxf(m, p0), p1);
      float so  = __expf(m - nm);
      float s0e = __expf(p0 - nm);
      float s1e = __expf(p1 - nm);
      denom = denom*so + s0e + s1e;
      acc.x = acc.x*so + s0e*xa.x + s1e*xb.x;
      acc.y = acc.y*so + s0e*xa.y + s1e*xb.y;
      acc.z = acc.z*so + s0e*xa.z + s1e*xb.z;
      acc.w = acc.w*so + s0e*xa.w + s1e*xb.w;
      m = nm;
    }
    if (t < nk) {   // odd tail
      const float* e0 = ep + (size_t)t*ED;
      float4 c0 = *(const float4*)(e0+0), c1 = *(const float4*)(e0+4);
      float4 c2 = *(const float4*)(e0+8), c3 = *(const float4*)(e0+12);
      float4 xa = make_float4(bf2f(x0u.x), bf2f(x0u.y), bf2f(x0u.z), bf2f(x0u.w));
      float4 em = eemb16(wv, c0, c1, c2, c3);
      float4 z = make_float4(xa.x+xr4.x+em.x, xa.y+xr4.y+em.y, xa.z+xr4.z+em.z, xa.w+xr4.w+em.w);
      float p = head_logit(z, av);
      float nm = fmaxf(m, p);
      float so = __expf(m - nm);
      float sn = __expf(p - nm);
      denom = denom*so + sn;
      acc.x = acc.x*so + sn*xa.x;
      acc.y = acc.y*so + sn*xa.y;
      acc.z = acc.z*so + sn*xa.z;
      acc.w = acc.w*so + sn*xa.w;
      m = nm;
    }
  }
  float inv = 1.f / denom;
  float* hp = h + (size_t)n*HID + c4;
  float4 hv = *(const float4*)hp;
  float4 b4 = *(const float4*)(bias + c4);
  hv.x += acc.x*inv + b4.x;
  hv.y += acc.y*inv + b4.y;
  hv.z += acc.z*inv + b4.z;
  hv.w += acc.w*inv + b4.w;
  *(float4*)hp = hv;
  ushort4 hbv = make_ushort4(f2bf(hv.x), f2bf(hv.y), f2bf(hv.z), f2bf(hv.w));
  *(ushort4*)(hb + (size_t)n*HID + c4) = hbv;
}

// mean-pool numerator: run-accumulated atomics (batch is sorted)
__global__ __launch_bounds__(256) void k_pool(const float* __restrict__ h,
    const int* __restrict__ batch, float* __restrict__ hg) {
  int c = threadIdx.x;
  int per = (NN + gridDim.x - 1) / gridDim.x;
  int n0 = blockIdx.x * per, n1 = min(NN, n0 + per);
  if (n0 >= n1) return;
  int cur = batch[n0];
  float acc = 0.f;
  for (int n = n0; n < n1; ++n) {
    int b = batch[n];
    if (b != cur) { atomicAdd(&hg[(size_t)cur*HID + c], acc); acc = 0.f; cur = b; }
    acc += h[(size_t)n*HID + c];
  }
  atomicAdd(&hg[(size_t)cur*HID + c], acc);
}

// out = gelu(hg/cnt @ W1 + b1) @ W2 + b2 ; one block per graph
__global__ __launch_bounds__(256) void k_mlp(const float* __restrict__ hg, const int* __restrict__ cnt,
    const float* __restrict__ W1, const float* __restrict__ b1,
    const float* __restrict__ W2, const float* __restrict__ b2, float* __restrict__ out) {
  __shared__ float row[HID];
  __shared__ float zrow[HID];
  int b = blockIdx.x, c = threadIdx.x;
  float cn = (float)cnt[b]; cn = cn < 1.f ? 1.f : cn;
  row[c] = hg[(size_t)b*HID + c] / cn;
  __syncthreads();
  float acc = b1[c];
  for (int j = 0; j < HID; ++j) acc += row[j] * W1[(size_t)j*HID + c];
  float g = 0.5f * acc * (1.f + erff(acc * 0.70710678118654752440f));
  zrow[c] = g;
  __syncthreads();
  float acc2 = b2[c];
  for (int j = 0; j < HID; ++j) acc2 += zrow[j] * W2[(size_t)j*HID + c];
  out[(size_t)b*HID + c] = acc2;
}

extern "C" void kernel_launch(void* const* d_in, const int* in_sizes, int n_in,
                              void* d_out, int out_size, void* d_ws, size_t ws_size,
                              hipStream_t stream) {
  const float* x         = (const float*)d_in[0];
  const int*   edge_index= (const int*)  d_in[1];
  const float* edge_attr = (const float*)d_in[2];
  const int*   batch     = (const int*)  d_in[3];
  const float* node_W    = (const float*)d_in[4];
  const float* node_b    = (const float*)d_in[5];
  const float* edge_W    = (const float*)d_in[6];
  const float* edge_b    = (const float*)d_in[7];
  const float* Wl        = (const float*)d_in[8];
  const float* bl        = (const float*)d_in[9];
  const float* Wr        = (const float*)d_in[10];
  const float* br        = (const float*)d_in[11];
  const float* We        = (const float*)d_in[12];
  const float* att       = (const float*)d_in[13];
  const float* conv_bias = (const float*)d_in[14];
  const float* W1        = (const float*)d_in[15];
  const float* b1        = (const float*)d_in[16];
  const float* W2        = (const float*)d_in[17];
  const float* b2        = (const float*)d_in[18];
  const int* srcp = edge_index;
  const int* dstp = edge_index + NE;

  float* ws = (float*)d_ws;
  float* h      = ws + OFF_H;
  ushort_t* hb  = (ushort_t*)(ws + OFF_HB);
  float* ea_csr = ws + OFF_EACSR;
  float* loopea = ws + OFF_LOOPEA;
  float* hg     = ws + OFF_HG;
  ushort_t* xlb = (ushort_t*)(ws + OFF_XLB);
  ushort_t* xrb = (ushort_t*)(ws + OFF_XRB);
  ushort_t* Bt  = (ushort_t*)(ws + OFF_BT);
  int* ib       = (int*)(ws + OFF_INT);
  int* deg      = ib + IOFF_DEG;
  int* row_off  = ib + IOFF_ROWOFF;
  int* cursor   = ib + IOFF_CURSOR;
  int* csr_src  = ib + IOFF_CSRSRC;
  int* csr_eid  = ib + IOFF_CSREID;
  int* cnt      = ib + IOFF_CNT;

  // zero accumulators (must happen every launch; harness doesn't re-poison)
  k_zero<<<8, 256, 0, stream>>>(hg, NB*HID);
  k_zero<<<80, 256, 0, stream>>>((float*)deg, NN);

  k_wt<<<(6*HID*HID + 255)/256, 256, 0, stream>>>(Wl, Wr, Bt);
  k_node_embed<<<NN/4, 256, 0, stream>>>(x, node_W, node_b, h, hb);
  k_deg<<<1250, 256, 0, stream>>>(dstp, deg);
  k_cnt_bs<<<1, 64, 0, stream>>>(batch, cnt);
  k_scan<<<1, 1024, 0, stream>>>(deg, row_off, cursor);
  k_fill<<<1250, 256, 0, stream>>>(srcp, dstp, cursor, csr_src, csr_eid);
  k_edge_prep<<<(NN*64 + 255)/256, 256, 0, stream>>>(edge_attr, edge_W, edge_b,
      row_off, csr_eid, ea_csr, loopea);

  for (int l = 0; l < NL; ++l) {
    dim3 g((NN + 63)/64, 2);
    k_gemm_bf16<<<g, 256, 0, stream>>>(hb, Bt + (size_t)l*2*HID*HID,
        bl + (size_t)l*HID, br + (size_t)l*HID, xlb, xrb, NN);
    k_gat_fused<<<(NN*64 + 255)/256, 256, 0, stream>>>(xlb, xrb, ea_csr, loopea,
        row_off, csr_src,
        We + (size_t)l*ED*HID, att + (size_t)l*HEADS*CH,
        conv_bias + (size_t)l*HID, h, hb);
  }

  k_pool<<<80, 256, 0, stream>>>(h, batch, hg);
  k_mlp<<<NB, 256, 0, stream>>>(hg, cnt, W1, b1, W2, b2, (float*)d_out);
}